// Round 2
// baseline (59.885 us; speedup 1.0000x reference)
//
#include <hip/hip_runtime.h>

#define GRID_NUM 7
#define IMG_SIZE 448.0f
#define LAMBDA_COORD 5.0f
#define LAMBDA_NOOBJ 0.5f
#define NUM_CLASSES 20
#define YOLO_EPS 1e-12f

#define CPB 256  // cells per block == threads per block

__device__ __forceinline__ float iou_pair(float px, float py, float pw, float ph,
                                          float tx, float ty, float tw, float th) {
    const float gs = IMG_SIZE / (float)GRID_NUM;  // 64.0
    float cx1 = px * gs, cy1 = py * gs, w1 = pw * IMG_SIZE, h1 = ph * IMG_SIZE;
    float cx2 = tx * gs, cy2 = ty * gs, w2 = tw * IMG_SIZE, h2 = th * IMG_SIZE;
    float ix = fmaxf(fminf(cx1 + 0.5f * w1, cx2 + 0.5f * w2) -
                     fmaxf(cx1 - 0.5f * w1, cx2 - 0.5f * w2), 0.0f);
    float iy = fmaxf(fminf(cy1 + 0.5f * h1, cy2 + 0.5f * h2) -
                     fmaxf(cy1 - 0.5f * h1, cy2 - 0.5f * h2), 0.0f);
    float inter = ix * iy;
    float uni = w1 * h1 + w2 * h2 - inter;
    return inter / (uni + YOLO_EPS);
}

__global__ void __launch_bounds__(CPB) yolo_loss_kernel(
        const float* __restrict__ y_pre, const float* __restrict__ y_true,
        float* __restrict__ out, int ncells, float inv_b) {
    __shared__ float sp[CPB * 30];  // 30 KB staged y_pre slab
    __shared__ float wsum[CPB / 64];

    const int t = threadIdx.x;
    const size_t blockCell = (size_t)blockIdx.x * CPB;
    const int validCells = min(CPB, ncells - (int)blockCell);
    const int validF4 = (validCells * 30) / 4;  // float4s we may load (tail handled below)

    // ---- coalesced global->LDS stage of y_pre: 256*30 floats = 1920 float4 ----
    const float4* gsrc = reinterpret_cast<const float4*>(y_pre + blockCell * 30);
    float4* ldst = reinterpret_cast<float4*>(sp);
#pragma unroll
    for (int i = 0; i < 8; ++i) {
        int g = i * CPB + t;
        if (g < (CPB * 30) / 4) {
            if (g < validF4) ldst[g] = gsrc[g];
        }
    }
    // tail floats (validCells*30 may not be /4) — only matters in the last block
    if (validCells < CPB) {
        int rem_start = validF4 * 4, rem_end = validCells * 30;
        for (int f = rem_start + t; f < rem_end; f += CPB) sp[f] = y_pre[blockCell * 30 + f];
    }
    __syncthreads();

    float acc = 0.0f;
    if (t < validCells) {
        // LDS -> registers: 15x ds_read_b64 at stride-30 words (4-way aliasing, cheap)
        float p[30];
        const float2* pl = reinterpret_cast<const float2*>(sp + t * 30);
#pragma unroll
        for (int i = 0; i < 15; ++i) {
            float2 v = pl[i];
            p[2 * i]     = v.x;
            p[2 * i + 1] = v.y;
        }
        // y_true: direct from global (32B stride, half-coalesced, small share of traffic)
        const float* tbase = y_true + (blockCell + t) * 8;
        float4 t0 = *reinterpret_cast<const float4*>(tbase);
        float gh = tbase[4];
        float cls = t0.x;
        float gx = t0.y, gy = t0.z, gw = t0.w;

        bool obj = (cls != 0.0f);
        float iou0 = iou_pair(p[0], p[1], p[2], p[3], gx, gy, gw, gh);
        float iou1 = iou_pair(p[5], p[6], p[7], p[8], gx, gy, gw, gh);
        bool c0 = iou0 > iou1;

        float l = 0.0f;
        if (obj) {
            float conf_pre  = c0 ? p[4] : p[9];
            float conf_true = c0 ? iou0 : iou1;
            float dc = conf_pre - conf_true;
            l += dc * dc;
            float xp = c0 ? p[0] : p[5];
            float yp = c0 ? p[1] : p[6];
            float dx = xp - gx, dy = yp - gy;
            l += LAMBDA_COORD * (dx * dx + dy * dy);
            float wp = c0 ? p[2] : p[7];
            float hp = c0 ? p[3] : p[8];
            float sw = sqrtf(wp + YOLO_EPS) - sqrtf(gw + YOLO_EPS);
            float sh = sqrtf(hp + YOLO_EPS) - sqrtf(gh + YOLO_EPS);
            l += LAMBDA_COORD * (sw * sw + sh * sh);
            int ci = (int)cls - 1;
#pragma unroll
            for (int c = 0; c < NUM_CLASSES; ++c) {
                float tt = (c == ci) ? 1.0f : 0.0f;
                float dd = p[10 + c] - tt;
                l += dd * dd;
            }
        } else {
            l += LAMBDA_NOOBJ * (p[4] * p[4] + p[9] * p[9]);
        }
        acc = l * inv_b;
    }

    // wave-64 reduce -> per-wave LDS -> one atomic per block
#pragma unroll
    for (int off = 32; off > 0; off >>= 1)
        acc += __shfl_down(acc, off, 64);

    int lane = t & 63, wid = t >> 6;
    if (lane == 0) wsum[wid] = acc;
    __syncthreads();
    if (t == 0) {
        float s = 0.0f;
#pragma unroll
        for (int w = 0; w < CPB / 64; ++w) s += wsum[w];
        atomicAdd(out, s);
    }
}

extern "C" void kernel_launch(void* const* d_in, const int* in_sizes, int n_in,
                              void* d_out, int out_size, void* d_ws, size_t ws_size,
                              hipStream_t stream) {
    const float* y_pre  = (const float*)d_in[0];
    const float* y_true = (const float*)d_in[1];
    float* out = (float*)d_out;

    const int B = in_sizes[0] / (GRID_NUM * GRID_NUM * 30);  // 16384
    const int ncells = B * GRID_NUM * GRID_NUM;              // 802816 = 3136 * 256
    const float inv_b = 1.0f / (float)B;

    hipMemsetAsync(out, 0, sizeof(float), stream);

    const int grid = (ncells + CPB - 1) / CPB;
    yolo_loss_kernel<<<grid, CPB, 0, stream>>>(y_pre, y_true, out, ncells, inv_b);
}

// Round 3
// 36.994 us; speedup vs baseline: 1.6188x; 1.6188x over previous
//
#include <hip/hip_runtime.h>

#define GRID_NUM 7
#define IMG_SIZE 448.0f
#define LAMBDA_COORD 5.0f
#define LAMBDA_NOOBJ 0.5f
#define NUM_CLASSES 20
#define YOLO_EPS 1e-12f

#define TPB 256  // threads per block; each thread handles 2 cells

__device__ __forceinline__ float iou_pair(float px, float py, float pw, float ph,
                                          float tx, float ty, float tw, float th) {
    const float gs = IMG_SIZE / (float)GRID_NUM;  // 64.0
    float cx1 = px * gs, cy1 = py * gs, w1 = pw * IMG_SIZE, h1 = ph * IMG_SIZE;
    float cx2 = tx * gs, cy2 = ty * gs, w2 = tw * IMG_SIZE, h2 = th * IMG_SIZE;
    float ix = fmaxf(fminf(cx1 + 0.5f * w1, cx2 + 0.5f * w2) -
                     fmaxf(cx1 - 0.5f * w1, cx2 - 0.5f * w2), 0.0f);
    float iy = fmaxf(fminf(cy1 + 0.5f * h1, cy2 + 0.5f * h2) -
                     fmaxf(cy1 - 0.5f * h1, cy2 - 0.5f * h2), 0.0f);
    float inter = ix * iy;
    float uni = w1 * h1 + w2 * h2 - inter;
    return inter / (uni + YOLO_EPS);
}

__device__ __forceinline__ float cell_loss(const float* __restrict__ p,
                                           float cls, float gx, float gy,
                                           float gw, float gh) {
    bool obj = (cls != 0.0f);
    float iou0 = iou_pair(p[0], p[1], p[2], p[3], gx, gy, gw, gh);
    float iou1 = iou_pair(p[5], p[6], p[7], p[8], gx, gy, gw, gh);
    bool c0 = iou0 > iou1;

    float l = 0.0f;
    if (obj) {
        float conf_pre  = c0 ? p[4] : p[9];
        float conf_true = c0 ? iou0 : iou1;
        float dc = conf_pre - conf_true;
        l += dc * dc;
        float xp = c0 ? p[0] : p[5];
        float yp = c0 ? p[1] : p[6];
        float dx = xp - gx, dy = yp - gy;
        l += LAMBDA_COORD * (dx * dx + dy * dy);
        float wp = c0 ? p[2] : p[7];
        float hp = c0 ? p[3] : p[8];
        float sw = sqrtf(wp + YOLO_EPS) - sqrtf(gw + YOLO_EPS);
        float sh = sqrtf(hp + YOLO_EPS) - sqrtf(gh + YOLO_EPS);
        l += LAMBDA_COORD * (sw * sw + sh * sh);
        int ci = (int)cls - 1;
#pragma unroll
        for (int c = 0; c < NUM_CLASSES; ++c) {
            float tt = (c == ci) ? 1.0f : 0.0f;
            float dd = p[10 + c] - tt;
            l += dd * dd;
        }
    } else {
        l += LAMBDA_NOOBJ * (p[4] * p[4] + p[9] * p[9]);
    }
    return l;
}

__global__ void __launch_bounds__(TPB) yolo_main(
        const float* __restrict__ y_pre, const float* __restrict__ y_true,
        float* __restrict__ partial, int nthreads) {
    int g = blockIdx.x * TPB + threadIdx.x;
    float acc = 0.0f;

    if (g < nthreads) {
        // 2 cells per thread: y_pre = 60 floats = 15 float4 (480B, 16B-aligned)
        const float4* pp = reinterpret_cast<const float4*>(y_pre + (size_t)g * 60);
        float p[60];
#pragma unroll
        for (int i = 0; i < 15; ++i) {
            float4 v = pp[i];
            p[4 * i]     = v.x;
            p[4 * i + 1] = v.y;
            p[4 * i + 2] = v.z;
            p[4 * i + 3] = v.w;
        }
        // y_true: 2 cells = 16 floats = 4 float4 = exactly one 64B line per thread
        const float4* tp = reinterpret_cast<const float4*>(y_true + (size_t)g * 16);
        float4 t0 = tp[0];  // cell0: cls, x, y, w
        float4 t1 = tp[1];  // cell0: h, ...
        float4 t2 = tp[2];  // cell1: cls, x, y, w
        float4 t3 = tp[3];  // cell1: h, ...
        (void)t3;

        acc  = cell_loss(p,      t0.x, t0.y, t0.z, t0.w, t1.x);
        acc += cell_loss(p + 30, t2.x, t2.y, t2.z, t2.w, t3.x);
    }

    // wave-64 reduce -> per-wave LDS -> single partial write per block (NO atomic)
#pragma unroll
    for (int off = 32; off > 0; off >>= 1)
        acc += __shfl_down(acc, off, 64);

    __shared__ float wsum[TPB / 64];
    int lane = threadIdx.x & 63, wid = threadIdx.x >> 6;
    if (lane == 0) wsum[wid] = acc;
    __syncthreads();
    if (threadIdx.x == 0) {
        float s = 0.0f;
#pragma unroll
        for (int w = 0; w < TPB / 64; ++w) s += wsum[w];
        partial[blockIdx.x] = s;
    }
}

__global__ void __launch_bounds__(256) yolo_reduce(
        const float* __restrict__ partial, float* __restrict__ out,
        int n, float inv_b) {
    float s = 0.0f;
    for (int i = threadIdx.x; i < n; i += 256) s += partial[i];
#pragma unroll
    for (int off = 32; off > 0; off >>= 1)
        s += __shfl_down(s, off, 64);
    __shared__ float wsum[4];
    int lane = threadIdx.x & 63, wid = threadIdx.x >> 6;
    if (lane == 0) wsum[wid] = s;
    __syncthreads();
    if (threadIdx.x == 0)
        out[0] = (wsum[0] + wsum[1] + wsum[2] + wsum[3]) * inv_b;
}

extern "C" void kernel_launch(void* const* d_in, const int* in_sizes, int n_in,
                              void* d_out, int out_size, void* d_ws, size_t ws_size,
                              hipStream_t stream) {
    const float* y_pre  = (const float*)d_in[0];
    const float* y_true = (const float*)d_in[1];
    float* out = (float*)d_out;
    float* partial = (float*)d_ws;

    const int B = in_sizes[0] / (GRID_NUM * GRID_NUM * 30);  // 16384
    const int ncells = B * GRID_NUM * GRID_NUM;              // 802816
    const int nthreads = ncells / 2;                         // 401408 (2 cells/thread)
    const float inv_b = 1.0f / (float)B;

    const int grid = (nthreads + TPB - 1) / TPB;             // 1568
    yolo_main<<<grid, TPB, 0, stream>>>(y_pre, y_true, partial, nthreads);
    yolo_reduce<<<1, 256, 0, stream>>>(partial, out, grid, inv_b);
}

// Round 4
// 28.189 us; speedup vs baseline: 2.1245x; 1.3124x over previous
//
#include <hip/hip_runtime.h>

#define GRID_NUM 7
#define IMG_SIZE 448.0f
#define LAMBDA_COORD 5.0f
#define LAMBDA_NOOBJ 0.5f
#define NUM_CLASSES 20
#define YOLO_EPS 1e-12f

#define TPB 256
#define WPB 4  // waves per block; each wave owns 64 cells, staged per-wave (no barriers)

__device__ __forceinline__ float iou_pair(float px, float py, float pw, float ph,
                                          float tx, float ty, float tw, float th) {
    const float gs = IMG_SIZE / (float)GRID_NUM;  // 64.0
    float cx1 = px * gs, cy1 = py * gs, w1 = pw * IMG_SIZE, h1 = ph * IMG_SIZE;
    float cx2 = tx * gs, cy2 = ty * gs, w2 = tw * IMG_SIZE, h2 = th * IMG_SIZE;
    float ix = fmaxf(fminf(cx1 + 0.5f * w1, cx2 + 0.5f * w2) -
                     fmaxf(cx1 - 0.5f * w1, cx2 - 0.5f * w2), 0.0f);
    float iy = fmaxf(fminf(cy1 + 0.5f * h1, cy2 + 0.5f * h2) -
                     fmaxf(cy1 - 0.5f * h1, cy2 - 0.5f * h2), 0.0f);
    float inter = ix * iy;
    float uni = w1 * h1 + w2 * h2 - inter;
    return inter / (uni + YOLO_EPS);
}

__device__ __forceinline__ float cell_loss(const float* __restrict__ p,
                                           float cls, float gx, float gy,
                                           float gw, float gh) {
    bool obj = (cls != 0.0f);
    float iou0 = iou_pair(p[0], p[1], p[2], p[3], gx, gy, gw, gh);
    float iou1 = iou_pair(p[5], p[6], p[7], p[8], gx, gy, gw, gh);
    bool c0 = iou0 > iou1;

    float l = 0.0f;
    if (obj) {
        float conf_pre  = c0 ? p[4] : p[9];
        float conf_true = c0 ? iou0 : iou1;
        float dc = conf_pre - conf_true;
        l += dc * dc;
        float xp = c0 ? p[0] : p[5];
        float yp = c0 ? p[1] : p[6];
        float dx = xp - gx, dy = yp - gy;
        l += LAMBDA_COORD * (dx * dx + dy * dy);
        float wp = c0 ? p[2] : p[7];
        float hp = c0 ? p[3] : p[8];
        float sw = sqrtf(wp + YOLO_EPS) - sqrtf(gw + YOLO_EPS);
        float sh = sqrtf(hp + YOLO_EPS) - sqrtf(gh + YOLO_EPS);
        l += LAMBDA_COORD * (sw * sw + sh * sh);
        int ci = (int)cls - 1;
#pragma unroll
        for (int c = 0; c < NUM_CLASSES; ++c) {
            float tt = (c == ci) ? 1.0f : 0.0f;
            float dd = p[10 + c] - tt;
            l += dd * dd;
        }
    } else {
        l += LAMBDA_NOOBJ * (p[4] * p[4] + p[9] * p[9]);
    }
    return l;
}

__global__ void __launch_bounds__(TPB) yolo_main(
        const float* __restrict__ y_pre, const float* __restrict__ y_true,
        float* __restrict__ partial) {
    // per-wave staging region: 64 cells * 30 floats = 1920 floats = 7680 B
    __shared__ __align__(16) float sp[WPB][1920];

    const int t = threadIdx.x;
    const int lane = t & 63;
    const int w = t >> 6;
    const size_t waveCell = (size_t)blockIdx.x * TPB + (size_t)w * 64;

    // ---- coalesced global->LDS stage (per-wave, linear, no barrier needed) ----
    // 480 float4 per wave = 7 full rounds of 64 lanes + half round of 32
    const float4* gsrc = reinterpret_cast<const float4*>(y_pre + waveCell * 30);
    float* lbase = sp[w];
#pragma unroll
    for (int i = 0; i < 7; ++i) {
        __builtin_amdgcn_global_load_lds(
            (const __attribute__((address_space(1))) void*)(gsrc + i * 64 + lane),
            (__attribute__((address_space(3))) void*)(lbase + i * 256),
            16, 0, 0);
    }
    if (lane < 32) {
        __builtin_amdgcn_global_load_lds(
            (const __attribute__((address_space(1))) void*)(gsrc + 448 + lane),
            (__attribute__((address_space(3))) void*)(lbase + 1792),
            16, 0, 0);
    }

    // y_true direct (issued before the wait so it overlaps staging):
    // 2 lanes share a 64B line -> half-coalesced, only ~25% of traffic
    const size_t cell = waveCell + lane;
    const float* tbase = y_true + cell * 8;
    float4 t0 = *reinterpret_cast<const float4*>(tbase);  // cls, x, y, w
    float gh = tbase[4];

    asm volatile("s_waitcnt vmcnt(0)" ::: "memory");

    // ---- LDS -> registers: 15x ds_read_b64 at stride-30 words (4-way aliasing) ----
    float p[30];
    const float2* pl = reinterpret_cast<const float2*>(lbase + lane * 30);
#pragma unroll
    for (int i = 0; i < 15; ++i) {
        float2 v = pl[i];
        p[2 * i]     = v.x;
        p[2 * i + 1] = v.y;
    }

    float acc = cell_loss(p, t0.x, t0.y, t0.z, t0.w, gh);

    // wave-64 reduce; each wave writes its own partial (no cross-wave sync)
#pragma unroll
    for (int off = 32; off > 0; off >>= 1)
        acc += __shfl_down(acc, off, 64);

    if (lane == 0)
        partial[blockIdx.x * WPB + w] = acc;
}

__global__ void __launch_bounds__(256) yolo_reduce(
        const float* __restrict__ partial, float* __restrict__ out,
        int n4, float inv_b) {
    // n4 = number of float4s in partial[]
    float s = 0.0f;
    const float4* p4 = reinterpret_cast<const float4*>(partial);
    for (int i = threadIdx.x; i < n4; i += 256) {
        float4 v = p4[i];
        s += v.x + v.y + v.z + v.w;
    }
#pragma unroll
    for (int off = 32; off > 0; off >>= 1)
        s += __shfl_down(s, off, 64);
    __shared__ float wsum[4];
    int lane = threadIdx.x & 63, wid = threadIdx.x >> 6;
    if (lane == 0) wsum[wid] = s;
    __syncthreads();
    if (threadIdx.x == 0)
        out[0] = (wsum[0] + wsum[1] + wsum[2] + wsum[3]) * inv_b;
}

extern "C" void kernel_launch(void* const* d_in, const int* in_sizes, int n_in,
                              void* d_out, int out_size, void* d_ws, size_t ws_size,
                              hipStream_t stream) {
    const float* y_pre  = (const float*)d_in[0];
    const float* y_true = (const float*)d_in[1];
    float* out = (float*)d_out;
    float* partial = (float*)d_ws;

    const int B = in_sizes[0] / (GRID_NUM * GRID_NUM * 30);  // 16384
    const int ncells = B * GRID_NUM * GRID_NUM;              // 802816 (divisible by 256)
    const float inv_b = 1.0f / (float)B;

    const int grid = ncells / TPB;                           // 3136
    const int npartial = grid * WPB;                         // 12544 (divisible by 4)

    yolo_main<<<grid, TPB, 0, stream>>>(y_pre, y_true, partial);
    yolo_reduce<<<1, 256, 0, stream>>>(partial, out, npartial / 4, inv_b);
}

// Round 5
// 25.488 us; speedup vs baseline: 2.3496x; 1.1060x over previous
//
#include <hip/hip_runtime.h>

#define GRID_NUM 7
#define IMG_SIZE 448.0f
#define LAMBDA_COORD 5.0f
#define LAMBDA_NOOBJ 0.5f
#define NUM_CLASSES 20
#define YOLO_EPS 1e-12f

#define TPB 256
#define WPB 4  // waves per block; each wave owns 64 cells, staged per-wave

__device__ __forceinline__ float iou_pair(float px, float py, float pw, float ph,
                                          float tx, float ty, float tw, float th) {
    const float gs = IMG_SIZE / (float)GRID_NUM;  // 64.0
    float cx1 = px * gs, cy1 = py * gs, w1 = pw * IMG_SIZE, h1 = ph * IMG_SIZE;
    float cx2 = tx * gs, cy2 = ty * gs, w2 = tw * IMG_SIZE, h2 = th * IMG_SIZE;
    float ix = fmaxf(fminf(cx1 + 0.5f * w1, cx2 + 0.5f * w2) -
                     fmaxf(cx1 - 0.5f * w1, cx2 - 0.5f * w2), 0.0f);
    float iy = fmaxf(fminf(cy1 + 0.5f * h1, cy2 + 0.5f * h2) -
                     fmaxf(cy1 - 0.5f * h1, cy2 - 0.5f * h2), 0.0f);
    float inter = ix * iy;
    float uni = w1 * h1 + w2 * h2 - inter;
    return inter / (uni + YOLO_EPS);
}

__device__ __forceinline__ float cell_loss(const float* __restrict__ p,
                                           float cls, float gx, float gy,
                                           float gw, float gh) {
    bool obj = (cls != 0.0f);
    float iou0 = iou_pair(p[0], p[1], p[2], p[3], gx, gy, gw, gh);
    float iou1 = iou_pair(p[5], p[6], p[7], p[8], gx, gy, gw, gh);
    bool c0 = iou0 > iou1;

    float l = 0.0f;
    if (obj) {
        float conf_pre  = c0 ? p[4] : p[9];
        float conf_true = c0 ? iou0 : iou1;
        float dc = conf_pre - conf_true;
        l += dc * dc;
        float xp = c0 ? p[0] : p[5];
        float yp = c0 ? p[1] : p[6];
        float dx = xp - gx, dy = yp - gy;
        l += LAMBDA_COORD * (dx * dx + dy * dy);
        float wp = c0 ? p[2] : p[7];
        float hp = c0 ? p[3] : p[8];
        float sw = sqrtf(wp + YOLO_EPS) - sqrtf(gw + YOLO_EPS);
        float sh = sqrtf(hp + YOLO_EPS) - sqrtf(gh + YOLO_EPS);
        l += LAMBDA_COORD * (sw * sw + sh * sh);
        int ci = (int)cls - 1;
#pragma unroll
        for (int c = 0; c < NUM_CLASSES; ++c) {
            float tt = (c == ci) ? 1.0f : 0.0f;
            float dd = p[10 + c] - tt;
            l += dd * dd;
        }
    } else {
        l += LAMBDA_NOOBJ * (p[4] * p[4] + p[9] * p[9]);
    }
    return l;
}

__global__ void __launch_bounds__(TPB) yolo_main(
        const float* __restrict__ y_pre, const float* __restrict__ y_true,
        float* __restrict__ partial) {
    // per-wave staging region: 64 cells * 30 floats = 1920 floats = 7680 B
    __shared__ __align__(16) float sp[WPB][1920];
    __shared__ float wsum[WPB];

    const int t = threadIdx.x;
    const int lane = t & 63;
    const int w = t >> 6;
    const size_t waveCell = (size_t)blockIdx.x * TPB + (size_t)w * 64;

    // ---- coalesced global->LDS stage (per-wave, linear, no barrier needed) ----
    const float4* gsrc = reinterpret_cast<const float4*>(y_pre + waveCell * 30);
    float* lbase = sp[w];
#pragma unroll
    for (int i = 0; i < 7; ++i) {
        __builtin_amdgcn_global_load_lds(
            (const __attribute__((address_space(1))) void*)(gsrc + i * 64 + lane),
            (__attribute__((address_space(3))) void*)(lbase + i * 256),
            16, 0, 0);
    }
    if (lane < 32) {
        __builtin_amdgcn_global_load_lds(
            (const __attribute__((address_space(1))) void*)(gsrc + 448 + lane),
            (__attribute__((address_space(3))) void*)(lbase + 1792),
            16, 0, 0);
    }

    // y_true direct (issued before the wait so it overlaps staging)
    const size_t cell = waveCell + lane;
    const float* tbase = y_true + cell * 8;
    float4 t0 = *reinterpret_cast<const float4*>(tbase);  // cls, x, y, w
    float gh = tbase[4];

    asm volatile("s_waitcnt vmcnt(0)" ::: "memory");

    // ---- LDS -> registers: 15x ds_read_b64 at stride-30 words ----
    float p[30];
    const float2* pl = reinterpret_cast<const float2*>(lbase + lane * 30);
#pragma unroll
    for (int i = 0; i < 15; ++i) {
        float2 v = pl[i];
        p[2 * i]     = v.x;
        p[2 * i + 1] = v.y;
    }

    float acc = cell_loss(p, t0.x, t0.y, t0.z, t0.w, gh);

    // wave-64 reduce -> cross-wave LDS reduce -> ONE partial per block
#pragma unroll
    for (int off = 32; off > 0; off >>= 1)
        acc += __shfl_down(acc, off, 64);

    if (lane == 0) wsum[w] = acc;
    __syncthreads();
    if (t == 0)
        partial[blockIdx.x] = wsum[0] + wsum[1] + wsum[2] + wsum[3];
}

__global__ void __launch_bounds__(256) yolo_reduce(
        const float* __restrict__ partial, float* __restrict__ out,
        int n4, float inv_b) {
    // n4 = 784 float4s (3136 floats); 784 = 3*256 + 16.
    // Issue all 4 loads independently before any use -> one latency round.
    const float4* p4 = reinterpret_cast<const float4*>(partial);
    const int i = threadIdx.x;
    float4 a = p4[i];
    float4 b = p4[i + 256];
    float4 c = p4[i + 512];
    float4 d = (i + 768 < n4) ? p4[i + 768] : make_float4(0.f, 0.f, 0.f, 0.f);

    float s = (a.x + a.y + a.z + a.w) + (b.x + b.y + b.z + b.w) +
              (c.x + c.y + c.z + c.w) + (d.x + d.y + d.z + d.w);

#pragma unroll
    for (int off = 32; off > 0; off >>= 1)
        s += __shfl_down(s, off, 64);

    __shared__ float wsum[4];
    int lane = threadIdx.x & 63, wid = threadIdx.x >> 6;
    if (lane == 0) wsum[wid] = s;
    __syncthreads();
    if (threadIdx.x == 0)
        out[0] = (wsum[0] + wsum[1] + wsum[2] + wsum[3]) * inv_b;
}

extern "C" void kernel_launch(void* const* d_in, const int* in_sizes, int n_in,
                              void* d_out, int out_size, void* d_ws, size_t ws_size,
                              hipStream_t stream) {
    const float* y_pre  = (const float*)d_in[0];
    const float* y_true = (const float*)d_in[1];
    float* out = (float*)d_out;
    float* partial = (float*)d_ws;

    const int B = in_sizes[0] / (GRID_NUM * GRID_NUM * 30);  // 16384
    const int ncells = B * GRID_NUM * GRID_NUM;              // 802816 (divisible by 256)
    const float inv_b = 1.0f / (float)B;

    const int grid = ncells / TPB;                           // 3136
    yolo_main<<<grid, TPB, 0, stream>>>(y_pre, y_true, partial);
    yolo_reduce<<<1, 256, 0, stream>>>(partial, out, grid / 4, inv_b);
}